// Round 2
// baseline (642.507 us; speedup 1.0000x reference)
//
#include <hip/hip_runtime.h>

#define DM 1024
#define SEQ 2048
#define NH 16
#define DK 64

typedef __bf16 bf16x8 __attribute__((ext_vector_type(8)));
typedef float f32x4 __attribute__((ext_vector_type(4)));

__device__ inline unsigned short f2bf(float f) {
    unsigned u = __float_as_uint(f);
    u += 0x7fffu + ((u >> 16) & 1u);
    return (unsigned short)(u >> 16);
}

// C[M,N] = A[M,K] @ W[N,K]^T + bias[N]
// A_BF16: A source is bf16 (ushort) else fp32.  OUT_F32: store fp32 else bf16.
template <bool A_BF16, bool OUT_F32>
__global__ __launch_bounds__(256) void gemm_bt(const void* __restrict__ Av,
                                               const float* __restrict__ W,
                                               const float* __restrict__ bias,
                                               void* __restrict__ Cv,
                                               int M, int N, int K) {
    const int LDT = 40;  // padded bf16 row stride (32 + 8): 2-way-max bank aliasing
    __shared__ unsigned short lds_a[128 * LDT];
    __shared__ unsigned short lds_w[128 * LDT];

    const int t = threadIdx.x;
    const int lane = t & 63;
    const int w = t >> 6;
    const int wr = w >> 1, wc = w & 1;
    const int rowBase = blockIdx.x * 128;
    const int colBase = blockIdx.y * 128;
    const int l15 = lane & 15;
    const int lg = lane >> 4;

    f32x4 acc[4][4] = {};

    for (int k0 = 0; k0 < K; k0 += 32) {
        // stage A tile 128x32 and W tile 128x32 (convert to bf16)
#pragma unroll
        for (int i = 0; i < 4; ++i) {
            int slot = t + 256 * i;      // 0..1023, 8 slots of 4 elems per row
            int r = slot >> 3;
            int c4 = (slot & 7) * 4;
            ushort4 sv;
            if (A_BF16) {
                const unsigned short* Ab =
                    (const unsigned short*)Av + (size_t)(rowBase + r) * K + k0 + c4;
                sv = *(const ushort4*)Ab;
            } else {
                const float* Af = (const float*)Av + (size_t)(rowBase + r) * K + k0 + c4;
                float4 vv = *(const float4*)Af;
                sv.x = f2bf(vv.x); sv.y = f2bf(vv.y); sv.z = f2bf(vv.z); sv.w = f2bf(vv.w);
            }
            *(ushort4*)&lds_a[r * LDT + c4] = sv;

            const float* Wf = W + (size_t)(colBase + r) * K + k0 + c4;
            float4 wv = *(const float4*)Wf;
            ushort4 swv;
            swv.x = f2bf(wv.x); swv.y = f2bf(wv.y); swv.z = f2bf(wv.z); swv.w = f2bf(wv.w);
            *(ushort4*)&lds_w[r * LDT + c4] = swv;
        }
        __syncthreads();

        const unsigned short* pa = &lds_a[(wr * 64 + l15) * LDT + lg * 8];
        const unsigned short* pw = &lds_w[(wc * 64 + l15) * LDT + lg * 8];
        bf16x8 af[4], wf[4];
#pragma unroll
        for (int m = 0; m < 4; ++m) af[m] = *(const bf16x8*)(pa + m * 16 * LDT);
#pragma unroll
        for (int n = 0; n < 4; ++n) wf[n] = *(const bf16x8*)(pw + n * 16 * LDT);
#pragma unroll
        for (int m = 0; m < 4; ++m)
#pragma unroll
            for (int n = 0; n < 4; ++n)
                acc[m][n] = __builtin_amdgcn_mfma_f32_16x16x32_bf16(af[m], wf[n],
                                                                    acc[m][n], 0, 0, 0);
        __syncthreads();
    }

    // epilogue: C row = (l>>4)*4 + j, col = l&15  (m89/m91-verified layout)
#pragma unroll
    for (int m = 0; m < 4; ++m) {
        int row = rowBase + wr * 64 + m * 16 + lg * 4;
#pragma unroll
        for (int n = 0; n < 4; ++n) {
            int col = colBase + wc * 64 + n * 16 + l15;
            float bv = bias[col];
#pragma unroll
            for (int j = 0; j < 4; ++j) {
                float val = acc[m][n][j] + bv;
                if (OUT_F32)
                    ((float*)Cv)[(size_t)(row + j) * N + col] = val;
                else
                    ((unsigned short*)Cv)[(size_t)(row + j) * N + col] = f2bf(val);
            }
        }
    }
}

// V [B,S, H*64] bf16  ->  Vt [B*H, 64, S] bf16
__global__ __launch_bounds__(256) void transpose_v(const unsigned short* __restrict__ V,
                                                   unsigned short* __restrict__ Vt) {
    __shared__ unsigned short tile[64][65];
    int s0 = blockIdx.x * 64;
    int bh = blockIdx.y;
    int b = bh >> 4, h = bh & 15;
    int t = threadIdx.x;
#pragma unroll
    for (int i = 0; i < 8; ++i) {
        int slot = t + 256 * i;
        int s = slot >> 5;
        int d2 = (slot & 31) * 2;
        const unsigned short* src = V + (size_t)(b * SEQ + s0 + s) * DM + h * DK + d2;
        ushort2 v = *(const ushort2*)src;
        tile[s][d2] = v.x;
        tile[s][d2 + 1] = v.y;
    }
    __syncthreads();
#pragma unroll
    for (int i = 0; i < 8; ++i) {
        int slot = t + 256 * i;
        int d = slot >> 5;
        int s2 = (slot & 31) * 2;
        ushort2 v;
        v.x = tile[s2][d];
        v.y = tile[s2 + 1][d];
        unsigned short* dst = Vt + (size_t)(bh * DK + d) * SEQ + s0 + s2;
        *(ushort2*)dst = v;
    }
}

// Flash attention, causal. Q,K: [B,S,1024] bf16 (per-head stride 64).
// Vt: [B*H, 64, S] bf16.  X out: [B,S,1024] bf16.
__global__ __launch_bounds__(256) void attn(const unsigned short* __restrict__ Q,
                                            const unsigned short* __restrict__ K,
                                            const unsigned short* __restrict__ Vt,
                                            unsigned short* __restrict__ X) {
    __shared__ unsigned short p_lds[4][16 * 40];  // per-wave 16x32 P tile, padded
    int t = threadIdx.x;
    int lane = t & 63;
    int w = t >> 6;
    int l15 = lane & 15, lg = lane >> 4;
    int qb = blockIdx.x * 64;
    int bh = blockIdx.y;
    int b = bh >> 4, h = bh & 15;

    int qrow0 = qb + w * 16;
    const size_t qoff = (size_t)(b * SEQ + qrow0 + l15) * DM + h * DK + lg * 8;
    bf16x8 qf0 = *(const bf16x8*)(Q + qoff);
    bf16x8 qf1 = *(const bf16x8*)(Q + qoff + 32);

    f32x4 acc[4] = {};
    float mrow[4], lrow[4];
#pragma unroll
    for (int j = 0; j < 4; ++j) { mrow[j] = -1e30f; lrow[j] = 0.f; }

    unsigned short* pl = &p_lds[w][0];
    int qmax = qrow0 + 15;
    int nt = (qmax >> 5) + 1;

    for (int tile = 0; tile < nt; ++tile) {
        int kv0 = tile << 5;
        // --- scores for BOTH 16-kv subtiles first (single max per 32-kv tile;
        //     fixes the stale-P rescale bug: P in LDS must share acc's m) ---
        float sv[2][4];
#pragma unroll
        for (int sub = 0; sub < 2; ++sub) {
            int kv16 = kv0 + (sub << 4);
            const size_t koff = (size_t)(b * SEQ + kv16 + l15) * DM + h * DK + lg * 8;
            bf16x8 kf0 = *(const bf16x8*)(K + koff);
            bf16x8 kf1 = *(const bf16x8*)(K + koff + 32);
            f32x4 s = {};
            s = __builtin_amdgcn_mfma_f32_16x16x32_bf16(qf0, kf0, s, 0, 0, 0);
            s = __builtin_amdgcn_mfma_f32_16x16x32_bf16(qf1, kf1, s, 0, 0, 0);
            int kg = kv16 + l15;
#pragma unroll
            for (int j = 0; j < 4; ++j) {
                int qg = qrow0 + lg * 4 + j;
                sv[sub][j] = (kg <= qg) ? s[j] * 0.125f : -1e30f;
            }
        }

        // tile max over both subs, then across the 16-lane group (xor<16 keeps lg)
        float tm[4];
#pragma unroll
        for (int j = 0; j < 4; ++j) tm[j] = fmaxf(sv[0][j], sv[1][j]);
#pragma unroll
        for (int off = 1; off < 16; off <<= 1)
#pragma unroll
            for (int j = 0; j < 4; ++j)
                tm[j] = fmaxf(tm[j], __shfl_xor(tm[j], off, 64));

        float al[4], ts[4];
        float ps[2][4];
#pragma unroll
        for (int j = 0; j < 4; ++j) {
            float newm = fmaxf(mrow[j], tm[j]);
            al[j] = __expf(mrow[j] - newm);
            mrow[j] = newm;
            ps[0][j] = __expf(sv[0][j] - newm);
            ps[1][j] = __expf(sv[1][j] - newm);
            ts[j] = ps[0][j] + ps[1][j];
        }
#pragma unroll
        for (int off = 1; off < 16; off <<= 1)
#pragma unroll
            for (int j = 0; j < 4; ++j)
                ts[j] += __shfl_xor(ts[j], off, 64);
#pragma unroll
        for (int j = 0; j < 4; ++j) lrow[j] = lrow[j] * al[j] + ts[j];
#pragma unroll
        for (int d = 0; d < 4; ++d)
#pragma unroll
            for (int j = 0; j < 4; ++j) acc[d][j] *= al[j];
#pragma unroll
        for (int sub = 0; sub < 2; ++sub)
#pragma unroll
            for (int j = 0; j < 4; ++j)
                pl[(lg * 4 + j) * 40 + (sub << 4) + l15] = f2bf(ps[sub][j]);

        // PV: A = P (16q x 32kv), B = V (32kv x 16d) read from Vt rows
        bf16x8 pf = *(const bf16x8*)(pl + l15 * 40 + lg * 8);
#pragma unroll
        for (int d = 0; d < 4; ++d) {
            const size_t voff = (size_t)(bh * DK + d * 16 + l15) * SEQ + kv0 + lg * 8;
            bf16x8 vf = *(const bf16x8*)(Vt + voff);
            acc[d] = __builtin_amdgcn_mfma_f32_16x16x32_bf16(pf, vf, acc[d], 0, 0, 0);
        }
    }

#pragma unroll
    for (int d = 0; d < 4; ++d)
#pragma unroll
        for (int j = 0; j < 4; ++j) {
            int qg = qrow0 + lg * 4 + j;
            float val = acc[d][j] / lrow[j];
            X[(size_t)(b * SEQ + qg) * DM + h * DK + d * 16 + l15] = f2bf(val);
        }
}

extern "C" void kernel_launch(void* const* d_in, const int* in_sizes, int n_in,
                              void* d_out, int out_size, void* d_ws, size_t ws_size,
                              hipStream_t stream) {
    const float* q  = (const float*)d_in[0];
    const float* k  = (const float*)d_in[1];
    const float* v  = (const float*)d_in[2];
    const float* Wq = (const float*)d_in[4];
    const float* bq = (const float*)d_in[5];
    const float* Wk = (const float*)d_in[6];
    const float* bk = (const float*)d_in[7];
    const float* Wv = (const float*)d_in[8];
    const float* bv = (const float*)d_in[9];
    const float* Wo = (const float*)d_in[10];
    const float* bo = (const float*)d_in[11];

    const size_t NEL = (size_t)4 * SEQ * DM;  // 8,388,608 elems per buffer
    unsigned short* Qp = (unsigned short*)d_ws;
    unsigned short* Kp = Qp + NEL;
    unsigned short* Vp = Kp + NEL;
    unsigned short* Vt = Vp + NEL;
    unsigned short* Xp = Vp;  // reuse V's slot after transpose

    dim3 gg(64, 8), gb(256);
    hipLaunchKernelGGL((gemm_bt<false, false>), gg, gb, 0, stream, (const void*)q, Wq, bq, (void*)Qp, 8192, DM, DM);
    hipLaunchKernelGGL((gemm_bt<false, false>), gg, gb, 0, stream, (const void*)k, Wk, bk, (void*)Kp, 8192, DM, DM);
    hipLaunchKernelGGL((gemm_bt<false, false>), gg, gb, 0, stream, (const void*)v, Wv, bv, (void*)Vp, 8192, DM, DM);
    hipLaunchKernelGGL(transpose_v, dim3(32, 64), gb, 0, stream, Vp, Vt);
    hipLaunchKernelGGL(attn, dim3(32, 64), gb, 0, stream, Qp, Kp, Vt, Xp);
    hipLaunchKernelGGL((gemm_bt<true, true>), gg, gb, 0, stream, (const void*)Xp, Wo, bo, d_out, 8192, DM, DM);
}

// Round 3
// 417.935 us; speedup vs baseline: 1.5373x; 1.5373x over previous
//
#include <hip/hip_runtime.h>

#define DM 1024
#define SEQ 2048
#define NH 16
#define DK 64

typedef __bf16 bf16x8 __attribute__((ext_vector_type(8)));
typedef float f32x4 __attribute__((ext_vector_type(4)));

__device__ inline unsigned short f2bf(float f) {
    unsigned u = __float_as_uint(f);
    u += 0x7fffu + ((u >> 16) & 1u);
    return (unsigned short)(u >> 16);
}

// C[M,N] = A[M,K] @ W[N,K]^T + bias[N]
// A_BF16: A source is bf16 (ushort) else fp32.  OUT_F32: store fp32 else bf16.
template <bool A_BF16, bool OUT_F32>
__global__ __launch_bounds__(256) void gemm_bt(const void* __restrict__ Av,
                                               const float* __restrict__ W,
                                               const float* __restrict__ bias,
                                               void* __restrict__ Cv,
                                               int M, int N, int K) {
    const int LDT = 40;  // padded bf16 row stride (32 + 8): 2-way-max bank aliasing
    __shared__ unsigned short lds_a[128 * LDT];
    __shared__ unsigned short lds_w[128 * LDT];

    const int t = threadIdx.x;
    const int lane = t & 63;
    const int w = t >> 6;
    const int wr = w >> 1, wc = w & 1;
    const int rowBase = blockIdx.x * 128;
    const int colBase = blockIdx.y * 128;
    const int l15 = lane & 15;
    const int lg = lane >> 4;

    f32x4 acc[4][4] = {};

    for (int k0 = 0; k0 < K; k0 += 32) {
#pragma unroll
        for (int i = 0; i < 4; ++i) {
            int slot = t + 256 * i;      // 0..1023, 8 slots of 4 elems per row
            int r = slot >> 3;
            int c4 = (slot & 7) * 4;
            ushort4 sv;
            if (A_BF16) {
                const unsigned short* Ab =
                    (const unsigned short*)Av + (size_t)(rowBase + r) * K + k0 + c4;
                sv = *(const ushort4*)Ab;
            } else {
                const float* Af = (const float*)Av + (size_t)(rowBase + r) * K + k0 + c4;
                float4 vv = *(const float4*)Af;
                sv.x = f2bf(vv.x); sv.y = f2bf(vv.y); sv.z = f2bf(vv.z); sv.w = f2bf(vv.w);
            }
            *(ushort4*)&lds_a[r * LDT + c4] = sv;

            const float* Wf = W + (size_t)(colBase + r) * K + k0 + c4;
            float4 wv = *(const float4*)Wf;
            ushort4 swv;
            swv.x = f2bf(wv.x); swv.y = f2bf(wv.y); swv.z = f2bf(wv.z); swv.w = f2bf(wv.w);
            *(ushort4*)&lds_w[r * LDT + c4] = swv;
        }
        __syncthreads();

        const unsigned short* pa = &lds_a[(wr * 64 + l15) * LDT + lg * 8];
        const unsigned short* pw = &lds_w[(wc * 64 + l15) * LDT + lg * 8];
        bf16x8 af[4], wf[4];
#pragma unroll
        for (int m = 0; m < 4; ++m) af[m] = *(const bf16x8*)(pa + m * 16 * LDT);
#pragma unroll
        for (int n = 0; n < 4; ++n) wf[n] = *(const bf16x8*)(pw + n * 16 * LDT);
#pragma unroll
        for (int m = 0; m < 4; ++m)
#pragma unroll
            for (int n = 0; n < 4; ++n)
                acc[m][n] = __builtin_amdgcn_mfma_f32_16x16x32_bf16(af[m], wf[n],
                                                                    acc[m][n], 0, 0, 0);
        __syncthreads();
    }

#pragma unroll
    for (int m = 0; m < 4; ++m) {
        int row = rowBase + wr * 64 + m * 16 + lg * 4;
#pragma unroll
        for (int n = 0; n < 4; ++n) {
            int col = colBase + wc * 64 + n * 16 + l15;
            float bv = bias[col];
#pragma unroll
            for (int j = 0; j < 4; ++j) {
                float val = acc[m][n][j] + bv;
                if (OUT_F32)
                    ((float*)Cv)[(size_t)(row + j) * N + col] = val;
                else
                    ((unsigned short*)Cv)[(size_t)(row + j) * N + col] = f2bf(val);
            }
        }
    }
}

// V [B,S, H*64] bf16  ->  Vt [B*H, 64, S] bf16
__global__ __launch_bounds__(256) void transpose_v(const unsigned short* __restrict__ V,
                                                   unsigned short* __restrict__ Vt) {
    __shared__ unsigned short tile[64][65];
    int s0 = blockIdx.x * 64;
    int bh = blockIdx.y;
    int b = bh >> 4, h = bh & 15;
    int t = threadIdx.x;
#pragma unroll
    for (int i = 0; i < 8; ++i) {
        int slot = t + 256 * i;
        int s = slot >> 5;
        int d2 = (slot & 31) * 2;
        const unsigned short* src = V + (size_t)(b * SEQ + s0 + s) * DM + h * DK + d2;
        ushort2 v = *(const ushort2*)src;
        tile[s][d2] = v.x;
        tile[s][d2 + 1] = v.y;
    }
    __syncthreads();
#pragma unroll
    for (int i = 0; i < 8; ++i) {
        int slot = t + 256 * i;
        int d = slot >> 5;
        int s2 = (slot & 31) * 2;
        ushort2 v;
        v.x = tile[s2][d];
        v.y = tile[s2 + 1][d];
        unsigned short* dst = Vt + (size_t)(bh * DK + d) * SEQ + s0 + s2;
        *(ushort2*)dst = v;
    }
}

// Flash attention, causal, swapped-operand form.
// Q,K: [B,S,1024] bf16 (head stride 64).  Vt: [B*H, 64, S] bf16.  X: [B,S,1024] bf16.
// Each wave owns a 16-q tile; lane owns ONE q-row (q = qrow0 + (lane&15)).
// Work-balanced: wave processes the pair (qt, 127-qt) -> ~65 kv-tiles/wave uniform.
__global__ __launch_bounds__(256) void attn(const unsigned short* __restrict__ Q,
                                            const unsigned short* __restrict__ K,
                                            const unsigned short* __restrict__ Vt,
                                            unsigned short* __restrict__ X) {
    __shared__ unsigned short p_lds[4][16 * 40];  // per-wave P^T tile [16q][32kv+pad]
    const int t = threadIdx.x;
    const int lane = t & 63;
    const int w = t >> 6;
    const int l15 = lane & 15, lg = lane >> 4;
    const int bh = blockIdx.y;
    const int b = bh >> 4, h = bh & 15;
    unsigned short* pl = &p_lds[w][0];

    const int p = blockIdx.x * 4 + w;  // pair id 0..63

#pragma unroll
    for (int task = 0; task < 2; ++task) {
        const int qt = task == 0 ? p : 127 - p;  // 16-row q-tile index 0..127
        const int qrow0 = qt * 16;
        const int qg = qrow0 + l15;  // this lane's q row

        const size_t qoff = (size_t)(b * SEQ + qrow0 + l15) * DM + h * DK + lg * 8;
        const bf16x8 qf0 = *(const bf16x8*)(Q + qoff);
        const bf16x8 qf1 = *(const bf16x8*)(Q + qoff + 32);

        f32x4 acc[4] = {};
        float m = -1e30f, lsum = 0.f;
        const int nt = ((qrow0 + 15) >> 5) + 1;

        for (int tile = 0; tile < nt; ++tile) {
            const int kv0 = tile << 5;

            // issue all global loads up front (V is independent of softmax)
            bf16x8 kf[2][2];
#pragma unroll
            for (int s = 0; s < 2; ++s) {
                const size_t koff =
                    (size_t)(b * SEQ + kv0 + s * 16 + l15) * DM + h * DK + lg * 8;
                kf[s][0] = *(const bf16x8*)(K + koff);
                kf[s][1] = *(const bf16x8*)(K + koff + 32);
            }
            bf16x8 vf[4];
#pragma unroll
            for (int d = 0; d < 4; ++d) {
                const size_t voff = (size_t)(bh * DK + d * 16 + l15) * SEQ + kv0 + lg * 8;
                vf[d] = *(const bf16x8*)(Vt + voff);
            }

            // swapped QK^T: S^T[kv][q], lane holds col q=l15, rows kv = s*16+4*lg+j
            float sv[8];
#pragma unroll
            for (int s = 0; s < 2; ++s) {
                f32x4 st = {};
                st = __builtin_amdgcn_mfma_f32_16x16x32_bf16(kf[s][0], qf0, st, 0, 0, 0);
                st = __builtin_amdgcn_mfma_f32_16x16x32_bf16(kf[s][1], qf1, st, 0, 0, 0);
#pragma unroll
                for (int j = 0; j < 4; ++j) sv[s * 4 + j] = st[j] * 0.125f;
            }
            if (kv0 + 31 > qrow0) {  // wave-uniform: only diagonal tiles mask
#pragma unroll
                for (int s = 0; s < 2; ++s)
#pragma unroll
                    for (int j = 0; j < 4; ++j) {
                        int kvg = kv0 + s * 16 + 4 * lg + j;
                        if (kvg > qg) sv[s * 4 + j] = -1e30f;
                    }
            }

            // row max: 7 in-reg + 2 shuffles (all lanes with same l15 share q)
            float tm = sv[0];
#pragma unroll
            for (int r = 1; r < 8; ++r) tm = fmaxf(tm, sv[r]);
            tm = fmaxf(tm, __shfl_xor(tm, 16, 64));
            tm = fmaxf(tm, __shfl_xor(tm, 32, 64));

            const float newm = fmaxf(m, tm);
            const float al = __expf(m - newm);
            m = newm;
            float ps[8], ts = 0.f;
#pragma unroll
            for (int r = 0; r < 8; ++r) {
                ps[r] = __expf(sv[r] - newm);
                ts += ps[r];
            }
            ts += __shfl_xor(ts, 16, 64);
            ts += __shfl_xor(ts, 32, 64);
            lsum = lsum * al + ts;
#pragma unroll
            for (int d = 0; d < 4; ++d)
#pragma unroll
                for (int j = 0; j < 4; ++j) acc[d][j] *= al;

            // store P^T as [q][kv] (lane's 4 j-values are kv-contiguous): 2x b64
#pragma unroll
            for (int s = 0; s < 2; ++s) {
                ushort4 pk;
                pk.x = f2bf(ps[s * 4 + 0]);
                pk.y = f2bf(ps[s * 4 + 1]);
                pk.z = f2bf(ps[s * 4 + 2]);
                pk.w = f2bf(ps[s * 4 + 3]);
                *(ushort4*)&pl[l15 * 40 + s * 16 + 4 * lg] = pk;
            }
            // B-fragment read: P^T[kv=8*lg+i][q=l15] -> contiguous b128
            const bf16x8 pf = *(const bf16x8*)&pl[l15 * 40 + lg * 8];

            // PV: O^T = V^T . P^T  (A=V^T slice from Vt, B=P^T)
#pragma unroll
            for (int d = 0; d < 4; ++d)
                acc[d] = __builtin_amdgcn_mfma_f32_16x16x32_bf16(vf[d], pf, acc[d], 0, 0, 0);
        }

        // epilogue: lane holds O^T[d=dblk*16+4*lg+j][q=l15]; pack 4 bf16 per store
        const float inv = 1.0f / lsum;
#pragma unroll
        for (int d = 0; d < 4; ++d) {
            ushort4 o;
            o.x = f2bf(acc[d][0] * inv);
            o.y = f2bf(acc[d][1] * inv);
            o.z = f2bf(acc[d][2] * inv);
            o.w = f2bf(acc[d][3] * inv);
            *(ushort4*)&X[(size_t)(b * SEQ + qg) * DM + h * DK + d * 16 + 4 * lg] = o;
        }
    }
}

extern "C" void kernel_launch(void* const* d_in, const int* in_sizes, int n_in,
                              void* d_out, int out_size, void* d_ws, size_t ws_size,
                              hipStream_t stream) {
    const float* q  = (const float*)d_in[0];
    const float* k  = (const float*)d_in[1];
    const float* v  = (const float*)d_in[2];
    const float* Wq = (const float*)d_in[4];
    const float* bq = (const float*)d_in[5];
    const float* Wk = (const float*)d_in[6];
    const float* bk = (const float*)d_in[7];
    const float* Wv = (const float*)d_in[8];
    const float* bv = (const float*)d_in[9];
    const float* Wo = (const float*)d_in[10];
    const float* bo = (const float*)d_in[11];

    const size_t NEL = (size_t)4 * SEQ * DM;  // 8,388,608 elems per buffer
    unsigned short* Qp = (unsigned short*)d_ws;
    unsigned short* Kp = Qp + NEL;
    unsigned short* Vp = Kp + NEL;
    unsigned short* Vt = Vp + NEL;
    unsigned short* Xp = Vp;  // reuse V's slot after transpose

    dim3 gg(64, 8), gb(256);
    hipLaunchKernelGGL((gemm_bt<false, false>), gg, gb, 0, stream, (const void*)q, Wq, bq, (void*)Qp, 8192, DM, DM);
    hipLaunchKernelGGL((gemm_bt<false, false>), gg, gb, 0, stream, (const void*)k, Wk, bk, (void*)Kp, 8192, DM, DM);
    hipLaunchKernelGGL((gemm_bt<false, false>), gg, gb, 0, stream, (const void*)v, Wv, bv, (void*)Vp, 8192, DM, DM);
    hipLaunchKernelGGL(transpose_v, dim3(32, 64), gb, 0, stream, Vp, Vt);
    hipLaunchKernelGGL(attn, dim3(16, 64), gb, 0, stream, Qp, Kp, Vt, Xp);
    hipLaunchKernelGGL((gemm_bt<true, true>), gg, gb, 0, stream, (const void*)Xp, Wo, bo, d_out, 8192, DM, DM);
}